// Round 1
// baseline (436.682 us; speedup 1.0000x reference)
//
#include <hip/hip_runtime.h>
#include <hip/hip_bf16.h>

// Sinusoidal positional encoding (lat/lon variant):
//   out[b,s,2k]   = x[b,s,2k]   + sin(lat[b,s] * freq[k])
//   out[b,s,2k+1] = x[b,s,2k+1] + cos(lon[b,s] * freq[k])
//   freq[k] = 1e-4^(2k/512) = 2^(k * log2(1e-4)/256),  k in [0,256)
//
// Memory-bound streaming kernel: float4 I/O on x/out, float2 broadcast read
// of positions, hardware exp2/sin/cos for the encoding.

#define D_MODEL 512

__global__ __launch_bounds__(256) void sinpe_kernel(
    const float4* __restrict__ x4,
    const float2* __restrict__ pos2,
    float4* __restrict__ out4,
    int n4)  // number of float4 elements
{
    // log2(1e-4)/256 computed in double, rounded to f32
    const float C = -0.05190512648261504f;
    const int stride = gridDim.x * blockDim.x;
    for (int v = blockIdx.x * blockDim.x + threadIdx.x; v < n4; v += stride) {
        float4 xv = x4[v];
        int e   = v << 2;            // flat element index of .x
        int row = e >> 9;            // (b*2048 + s), since D_MODEL=512
        int k0  = (e & (D_MODEL - 1)) >> 1;  // pair index of first element

        float2 p = pos2[row];        // p.x = lat, p.y = lon (L2-resident broadcast)

        float f0 = exp2f((float)k0 * C);
        float f1 = exp2f((float)(k0 + 1) * C);

        float4 o;
        o.x = xv.x + __sinf(p.x * f0);
        o.y = xv.y + __cosf(p.y * f0);
        o.z = xv.z + __sinf(p.x * f1);
        o.w = xv.w + __cosf(p.y * f1);
        out4[v] = o;
    }
}

extern "C" void kernel_launch(void* const* d_in, const int* in_sizes, int n_in,
                              void* d_out, int out_size, void* d_ws, size_t ws_size,
                              hipStream_t stream) {
    const float4* x4   = (const float4*)d_in[0];   // (64,2048,512) f32
    const float2* pos2 = (const float2*)d_in[1];   // (64,2048,2) f32
    float4* out4       = (float4*)d_out;

    int n4 = out_size / 4;  // 16,777,216 float4s

    const int block = 256;
    int grid = (n4 + block - 1) / block;
    if (grid > 2048) grid = 2048;   // grid-stride; ~8 blocks/CU across 256 CUs

    sinpe_kernel<<<grid, block, 0, stream>>>(x4, pos2, out4, n4);
}

// Round 7
// 425.432 us; speedup vs baseline: 1.0264x; 1.0264x over previous
//
#include <hip/hip_runtime.h>
#include <hip/hip_bf16.h>

// Sinusoidal positional encoding (lat/lon variant):
//   out[b,s,2k]   = x[b,s,2k]   + sin(lat[b,s] * freq[k])
//   out[b,s,2k+1] = x[b,s,2k+1] + cos(lon[b,s] * freq[k])
//   freq[k] = 1e-4^(2k/512) = 2^(k * log2(1e-4)/256),  k in [0,256)
//
// Pure streaming kernel (memory-bound, ~513 MiB HBM traffic):
//  - float4 NT load/store on x/out (read-once / write-once streams),
//    via clang ext_vector_type (nontemporal builtins reject HIP_vector_type)
//  - float2 pos read is wave-uniform (one row spans 128 float4s) -> L2 broadcast
//  - k0 is loop-invariant (grid stride * 4 is a multiple of D_MODEL):
//    the two exp2f's are hoisted to once per thread, with 1/2pi folded in
//  - trig = v_mul + v_fract + v_sin/v_cos (hardware, input in revolutions)

#define D_MODEL 512

typedef float vfloat4 __attribute__((ext_vector_type(4)));

__global__ __launch_bounds__(256) void sinpe_kernel(
    const vfloat4* __restrict__ x4,
    const float2* __restrict__ pos2,
    vfloat4* __restrict__ out4,
    int n4)
{
    const float C      = -0.05190512648261504f;   // log2(1e-4)/256
    const float INV2PI =  0.15915494309189535f;   // 1/(2*pi)

    const int tid    = blockIdx.x * blockDim.x + threadIdx.x;
    const int stride = gridDim.x * blockDim.x;    // multiple of 128 float4s

    // Pair index for this thread's float4 — invariant across the grid-stride
    // loop because stride*4 elements is a multiple of D_MODEL.
    const int k0 = ((tid << 2) & (D_MODEL - 1)) >> 1;
    // freq[k]/2pi, so the trig argument is directly in revolutions.
    const float c0 = __builtin_amdgcn_exp2f((float)k0 * C) * INV2PI;
    const float c1 = __builtin_amdgcn_exp2f((float)(k0 + 1) * C) * INV2PI;

    for (int v = tid; v < n4; v += stride) {
        vfloat4 xv = __builtin_nontemporal_load(&x4[v]);
        int row = v >> 7;                 // 128 float4s per row (D_MODEL/4)
        float2 p = pos2[row];             // wave-uniform -> broadcast, cached

        // r in revolutions; fract -> [0,1) = hardware trig's sweet spot.
        // sin(2pi*fract(r)) == sin(2pi*r), same for cos.
        float r0 = __builtin_amdgcn_fractf(p.x * c0);
        float r1 = __builtin_amdgcn_fractf(p.y * c0);
        float r2 = __builtin_amdgcn_fractf(p.x * c1);
        float r3 = __builtin_amdgcn_fractf(p.y * c1);

        vfloat4 o;
        o.x = xv.x + __builtin_amdgcn_sinf(r0);
        o.y = xv.y + __builtin_amdgcn_cosf(r1);
        o.z = xv.z + __builtin_amdgcn_sinf(r2);
        o.w = xv.w + __builtin_amdgcn_cosf(r3);
        __builtin_nontemporal_store(o, &out4[v]);
    }
}

extern "C" void kernel_launch(void* const* d_in, const int* in_sizes, int n_in,
                              void* d_out, int out_size, void* d_ws, size_t ws_size,
                              hipStream_t stream) {
    const vfloat4* x4  = (const vfloat4*)d_in[0];  // (64,2048,512) f32
    const float2* pos2 = (const float2*)d_in[1];   // (64,2048,2) f32
    vfloat4* out4      = (vfloat4*)d_out;

    int n4 = out_size / 4;                          // 16,777,216

    const int block = 256;
    int grid = (n4 + block - 1) / block;
    if (grid > 2048) grid = 2048;                   // grid-stride, ~8 blocks/CU

    sinpe_kernel<<<grid, block, 0, stream>>>(x4, pos2, out4, n4);
}